// Round 1
// baseline (256.636 us; speedup 1.0000x reference)
//
#include <hip/hip_runtime.h>

// Problem constants
#define B_    1024
#define C_    128
#define ELL   16
#define EQ    3
#define E_    10
#define P3    23
#define P2    5
#define NWX   48      // EQ*ELL
#define NJ    768     // EQ*ELL*ELL
#define NJI   12288   // NJ*ELL

// ws layout (bytes)
#define WS_CNT   0
#define WS_LIST  64
#define WS_U3T   65536                         // mode-a: U3 transposed [k][ji], 1.13 MB
#define WS_V3G   (2u << 20)                    // mode-b: V3[e][c][ji], 62.9 MB
#define WS_NEED_B ((size_t)WS_V3G + (size_t)E_ * C_ * NJI * 4)

// ---------------------------------------------------------------------------
// K1: bucket batch indices by element (y is exact one-hot fp32)
__global__ __launch_bounds__(B_) void k_lists(const float* __restrict__ y,
                                              int* __restrict__ cnt_g,
                                              int* __restrict__ list_g) {
    __shared__ int lcnt[E_];
    const int t = threadIdx.x;
    if (t < E_) lcnt[t] = 0;
    __syncthreads();
    int e = 0;
    #pragma unroll
    for (int j = 1; j < E_; ++j)
        if (y[t * E_ + j] > 0.5f) e = j;
    int slot = atomicAdd(&lcnt[e], 1);
    list_g[e * B_ + slot] = t;
    __syncthreads();
    if (t < E_) cnt_g[t] = lcnt[t];
}

// ---------------------------------------------------------------------------
// K2 (mode b): V3g[e][c][ji] = sum_k U3[ji*23+k] * w_max[(e*23+k)*128+c]
// grid (24 ji-tiles of 512, E, 2 c-halves), 128 threads
__global__ __launch_bounds__(128) void k_v3g(const float* __restrict__ U3,
                                             const float* __restrict__ wmax,
                                             float* __restrict__ v3g) {
    __shared__ __align__(16) float U3L[P3 * 512];  // [k][ji_local]
    const int t  = threadIdx.x;
    const int jt = blockIdx.x, e = blockIdx.y, ch = blockIdx.z;

    // stage one U3 tile (512 rows x 23) with [ji][k] -> [k][ji] re-layout
    const float4* src = (const float4*)(U3 + (size_t)jt * 512 * P3);
    for (int r = 0; r < 23; ++r) {
        int f = t + 128 * r;          // f4 index within tile, 0..2943
        float4 u = src[f];
        int lf = 4 * f;
        #pragma unroll
        for (int q = 0; q < 4; ++q) {
            int lfq = lf + q;
            int ji = lfq / P3, k = lfq - ji * P3;
            U3L[k * 512 + ji] = ((const float*)&u)[q];
        }
    }
    __syncthreads();

    for (int ct = 0; ct < 8; ++ct) {
        const int c0 = ch * 64 + ct * 8;
        float4 acc[8];
        #pragma unroll
        for (int c8 = 0; c8 < 8; ++c8) acc[c8] = make_float4(0.f, 0.f, 0.f, 0.f);
        #pragma unroll
        for (int k = 0; k < P3; ++k) {
            float4 u = *(const float4*)(&U3L[k * 512 + 4 * t]);
            #pragma unroll
            for (int c8 = 0; c8 < 8; ++c8) {
                float w = wmax[(e * P3 + k) * C_ + c0 + c8];
                acc[c8].x += u.x * w; acc[c8].y += u.y * w;
                acc[c8].z += u.z * w; acc[c8].w += u.w * w;
            }
        }
        #pragma unroll
        for (int c8 = 0; c8 < 8; ++c8) {
            int c = c0 + c8;
            *(float4*)(&v3g[(size_t)(e * C_ + c) * NJI + jt * 512 + 4 * t]) = acc[c8];
        }
    }
}

// ---------------------------------------------------------------------------
// K2 (mode a): transpose U3 [ji][k] -> U3T [k][ji]   (282624 = 1104*256)
__global__ void k_transposeU3(const float* __restrict__ U3, float* __restrict__ U3T) {
    int o = blockIdx.x * 256 + threadIdx.x;
    if (o < NJI * P3) {
        int ji = o / P3, k = o - ji * P3;
        U3T[k * NJI + ji] = U3[o];
    }
}

// ---------------------------------------------------------------------------
// K3: main contraction. grid (C_, E_), 384 threads.
// LDS: V3L padded wx-stride 260 floats (260%32==4 -> conflict-free b128),
//      V2L flat, T2L for the nu=2 -> nu=1 exchange. Total 65,280 B.
__global__ __launch_bounds__(384, 3) void k_main(
    const float* __restrict__ x, const float* __restrict__ u3x,
    const float* __restrict__ U2, const float* __restrict__ U1,
    const float* __restrict__ wmax, const float* __restrict__ w2,
    const float* __restrict__ w1, const int* __restrict__ cnt_g,
    const int* __restrict__ list_g, float* __restrict__ out, int mode_b) {

    __shared__ __align__(16) float V3L[NWX * 260];  // 49,920 B
    __shared__ float V2L[NJ];                       //  3,072 B
    __shared__ float T2L[64 * 48];                  // 12,288 B

    const int t  = threadIdx.x;
    const int c  = blockIdx.x, e = blockIdx.y;
    const int wx = t >> 3, bs = t & 7;
    const int cnt = cnt_g[e];

    // ---- fill V3L ----
    if (mode_b) {
        const float4* src = (const float4*)(u3x + (size_t)(e * C_ + c) * NJI);
        #pragma unroll
        for (int r = 0; r < 8; ++r) {
            int f = t + 384 * r;                  // f4 index 0..3071
            float4 u = src[f];
            int ji0  = 4 * f;
            int addr = (ji0 >> 8) * 260 + (ji0 & 255);
            *(float4*)(&V3L[addr]) = u;
        }
    } else {
        // compute V3 from U3T directly (fallback)
        float4 acc[8];
        #pragma unroll
        for (int r = 0; r < 8; ++r) acc[r] = make_float4(0.f, 0.f, 0.f, 0.f);
        const float4* u3t4 = (const float4*)u3x;
        for (int k = 0; k < P3; ++k) {
            float wm = wmax[(e * P3 + k) * C_ + c];
            #pragma unroll
            for (int r = 0; r < 8; ++r) {
                float4 u = u3t4[k * 3072 + t + 384 * r];
                acc[r].x += u.x * wm; acc[r].y += u.y * wm;
                acc[r].z += u.z * wm; acc[r].w += u.w * wm;
            }
        }
        #pragma unroll
        for (int r = 0; r < 8; ++r) {
            int ji0  = 4 * (t + 384 * r);
            int addr = (ji0 >> 8) * 260 + (ji0 & 255);
            *(float4*)(&V3L[addr]) = acc[r];
        }
    }
    // ---- V2L[j] = sum_k U2[j*5+k] * w2[e,k,c] ----
    #pragma unroll
    for (int r = 0; r < 2; ++r) {
        int j = t + 384 * r;
        float s = 0.f;
        #pragma unroll
        for (int k = 0; k < P2; ++k)
            s += U2[j * P2 + k] * w2[(e * P2 + k) * C_ + c];
        V2L[j] = s;
    }
    const float w1s = w1[e * C_ + c];
    __syncthreads();

    // ---- chunk loop: 64 batch rows per chunk, 8 per thread ----
    for (int base = 0; base < cnt; base += 64) {
        float xr[8][16];
        #pragma unroll
        for (int r = 0; r < 8; ++r) {
            int slot = base + bs * 8 + r;
            if (slot < cnt) {
                int b = list_g[e * B_ + slot];
                const float4* xp = (const float4*)(x + ((size_t)b * C_ + c) * ELL);
                #pragma unroll
                for (int i4 = 0; i4 < 4; ++i4) {
                    float4 v = xp[i4];
                    xr[r][4 * i4 + 0] = v.x; xr[r][4 * i4 + 1] = v.y;
                    xr[r][4 * i4 + 2] = v.z; xr[r][4 * i4 + 3] = v.w;
                }
            } else {
                #pragma unroll
                for (int i = 0; i < 16; ++i) xr[r][i] = 0.f;
            }
        }

        float t2[8];
        #pragma unroll
        for (int r = 0; r < 8; ++r) t2[r] = 0.f;
        const float* v3p = &V3L[wx * 260];
        const float* v2p = &V2L[wx * 16];

        #pragma unroll
        for (int v = 0; v < 16; ++v) {
            float c2v = v2p[v];
            float s[8];
            #pragma unroll
            for (int r = 0; r < 8; ++r) s[r] = c2v;
            #pragma unroll
            for (int i4 = 0; i4 < 4; ++i4) {
                float4 u = *(const float4*)(v3p + v * 16 + 4 * i4);
                #pragma unroll
                for (int r = 0; r < 8; ++r) {
                    s[r] += u.x * xr[r][4 * i4 + 0];
                    s[r] += u.y * xr[r][4 * i4 + 1];
                    s[r] += u.z * xr[r][4 * i4 + 2];
                    s[r] += u.w * xr[r][4 * i4 + 3];
                }
            }
            #pragma unroll
            for (int r = 0; r < 8; ++r) t2[r] += s[r] * xr[r][v];
        }

        // exchange t2 (per-b 48 values spread over 48 wx lanes) via LDS
        #pragma unroll
        for (int r = 0; r < 8; ++r) T2L[(bs * 8 + r) * 48 + wx] = t2[r];
        __syncthreads();

        if (t < 192) {
            int bl = t / 3, w = t - 3 * bl;
            int slot = base + bl;
            if (slot < cnt) {
                int b = list_g[e * B_ + slot];
                const float* xp = x + ((size_t)b * C_ + c) * ELL;
                float t1 = 0.f;
                #pragma unroll
                for (int xx = 0; xx < 16; ++xx) {
                    float c1 = T2L[bl * 48 + w * 16 + xx] + U1[w * 16 + xx] * w1s;
                    t1 += c1 * xp[xx];
                }
                out[(size_t)b * (C_ * EQ) + c * EQ + w] = t1;
            }
        }
        __syncthreads();
    }
}

// ---------------------------------------------------------------------------
extern "C" void kernel_launch(void* const* d_in, const int* in_sizes, int n_in,
                              void* d_out, int out_size, void* d_ws, size_t ws_size,
                              hipStream_t stream) {
    const float* x    = (const float*)d_in[0];
    const float* y    = (const float*)d_in[1];
    const float* U3   = (const float*)d_in[2];
    const float* U2   = (const float*)d_in[3];
    const float* U1   = (const float*)d_in[4];
    const float* wmax = (const float*)d_in[5];
    const float* w2   = (const float*)d_in[6];
    const float* w1   = (const float*)d_in[7];
    float* out = (float*)d_out;
    char*  ws  = (char*)d_ws;

    int* cnt_g  = (int*)(ws + WS_CNT);
    int* list_g = (int*)(ws + WS_LIST);

    k_lists<<<1, B_, 0, stream>>>(y, cnt_g, list_g);

    if (ws_size >= WS_NEED_B) {
        float* v3g = (float*)(ws + WS_V3G);
        k_v3g<<<dim3(24, E_, 2), 128, 0, stream>>>(U3, wmax, v3g);
        k_main<<<dim3(C_, E_), 384, 0, stream>>>(x, v3g, U2, U1, wmax, w2, w1,
                                                 cnt_g, list_g, out, 1);
    } else {
        float* u3t = (float*)(ws + WS_U3T);
        k_transposeU3<<<1104, 256, 0, stream>>>(U3, u3t);
        k_main<<<dim3(C_, E_), 384, 0, stream>>>(x, u3t, U2, U1, wmax, w2, w1,
                                                 cnt_g, list_g, out, 0);
    }
}

// Round 3
// 166.249 us; speedup vs baseline: 1.5437x; 1.5437x over previous
//
#include <hip/hip_runtime.h>

// Problem constants
#define B_    1024
#define C_    128
#define ELL   16
#define EQ    3
#define E_    10
#define P3    23
#define P2    5
#define NJI   12288   // EQ*ELL*ELL*ELL

// ws layout (bytes)
#define WS_CNT   0
#define WS_LIST  64
#define WS_U3T   65536                         // mode-a: U3 transposed [k][ji], 1.13 MB
#define WS_V3G   (2u << 20)                    // mode-b: V3[e][c][ji], 62.9 MB
#define WS_NEED_B ((size_t)WS_V3G + (size_t)E_ * C_ * NJI * 4)

// ---------------------------------------------------------------------------
// K1: bucket batch indices by element (y is exact one-hot fp32)
__global__ __launch_bounds__(B_) void k_lists(const float* __restrict__ y,
                                              int* __restrict__ cnt_g,
                                              int* __restrict__ list_g) {
    __shared__ int lcnt[E_];
    const int t = threadIdx.x;
    if (t < E_) lcnt[t] = 0;
    __syncthreads();
    int e = 0;
    #pragma unroll
    for (int j = 1; j < E_; ++j)
        if (y[t * E_ + j] > 0.5f) e = j;
    int slot = atomicAdd(&lcnt[e], 1);
    list_g[e * B_ + slot] = t;
    __syncthreads();
    if (t < E_) cnt_g[t] = lcnt[t];
}

// ---------------------------------------------------------------------------
// K2 (mode b): v3g[(e*C+c)*NJI + ji] = sum_k U3[ji*23+k] * wmax[(e*23+k)*128+c]
// grid (24 ji-tiles of 512, E, 4 c-quarters), 256 threads.
// Each thread owns ji0 = jibase + 2t: reads the 46 consecutive floats
// (rows ji0 and ji0+1 of U3) into registers, loops 32 c values with wmax
// broadcast from LDS. Stores coalesced float2.
__global__ __launch_bounds__(256) void k_v3g(const float* __restrict__ U3,
                                             const float* __restrict__ wmax,
                                             float* __restrict__ v3g) {
    __shared__ float wsm[P3 * 32];
    const int t  = threadIdx.x;
    const int jibase = blockIdx.x * 512;
    const int e  = blockIdx.y;
    const int cq = blockIdx.z;          // c-quarter

    // stage wmax[e, :, cq*32 .. +32) -> wsm[k*32+cc]
    for (int idx = t; idx < P3 * 32; idx += 256) {
        int k = idx >> 5, cc = idx & 31;
        wsm[idx] = wmax[(e * P3 + k) * C_ + cq * 32 + cc];
    }

    // rows ji0 and ji0+1 of U3: 46 consecutive floats starting at ji0*23.
    // u46[k] = U3[ji0*23+k] (row ji0), u46[23+k] = U3[(ji0+1)*23+k] (row ji0+1)
    const int ji0 = jibase + 2 * t;
    float u46[46];
    const float* up = U3 + (size_t)ji0 * P3;
    #pragma unroll
    for (int q = 0; q < 46; ++q) u46[q] = up[q];
    __syncthreads();

    for (int cc = 0; cc < 32; ++cc) {
        const int c = cq * 32 + cc;
        float a0 = 0.f, a1 = 0.f;
        #pragma unroll
        for (int k = 0; k < P3; ++k) {
            float wk = wsm[k * 32 + cc];   // wave-uniform broadcast
            a0 += u46[k]      * wk;
            a1 += u46[23 + k] * wk;
        }
        float2 o; o.x = a0; o.y = a1;
        *(float2*)(&v3g[(size_t)(e * C_ + c) * NJI + ji0]) = o;
    }
}

// ---------------------------------------------------------------------------
// K2 (mode a): transpose U3 [ji][k] -> U3T [k][ji]   (282624 = 1104*256)
__global__ void k_transposeU3(const float* __restrict__ U3, float* __restrict__ U3T) {
    int o = blockIdx.x * 256 + threadIdx.x;
    if (o < NJI * P3) {
        int ji = o / P3, k = o - ji * P3;
        U3T[k * NJI + ji] = U3[o];
    }
}

// ---------------------------------------------------------------------------
// K3: main contraction. grid (C_, E_, EQ), 128 threads (2 waves).
// Each block handles one (c, e, w). V3 slice (16 x-rows x 256 (v,i)) in LDS
// with row stride 260 (260%32==4 -> 8 distinct rows/wave hit disjoint 4-bank
// groups -> conflict-free b128 reads; 8-lane same-address broadcast is free).
// Threads: xx = t>>3 in [0,16), bs = t&7; 4 batch rows per thread -> chunk=32.
__global__ __launch_bounds__(128, 4) void k_main(
    const float* __restrict__ x, const float* __restrict__ u3x,
    const float* __restrict__ U2, const float* __restrict__ U1,
    const float* __restrict__ wmax, const float* __restrict__ w2,
    const float* __restrict__ w1, const int* __restrict__ cnt_g,
    const int* __restrict__ list_g, float* __restrict__ out, int mode_b) {

    __shared__ __align__(16) float V3L[16 * 260];  // 16,640 B
    __shared__ float T2L[32 * 17];                 //  2,176 B

    const int t  = threadIdx.x;
    const int c  = blockIdx.x, e = blockIdx.y, w = blockIdx.z;
    const int xx = t >> 3, bs = t & 7;
    const int cnt = cnt_g[e];

    // ---- fill V3L (rows = xx in [0,16), cols = v*16+i in [0,256)) ----
    if (mode_b) {
        const float4* src = (const float4*)(u3x + (size_t)(e * C_ + c) * NJI + w * 4096);
        #pragma unroll
        for (int r = 0; r < 8; ++r) {
            int f = t + 128 * r;                   // f4 index 0..1023
            float4 u = src[f];
            int ji0  = 4 * f;
            int addr = (ji0 >> 8) * 260 + (ji0 & 255);
            *(float4*)(&V3L[addr]) = u;
        }
    } else {
        // from U3T [k][NJI], columns w*4096 .. +4096
        float4 acc[8];
        #pragma unroll
        for (int r = 0; r < 8; ++r) acc[r] = make_float4(0.f, 0.f, 0.f, 0.f);
        for (int k = 0; k < P3; ++k) {
            float wm = wmax[(e * P3 + k) * C_ + c];
            const float4* u3t4 = (const float4*)(u3x + (size_t)k * NJI + w * 4096);
            #pragma unroll
            for (int r = 0; r < 8; ++r) {
                float4 u = u3t4[t + 128 * r];
                acc[r].x += u.x * wm; acc[r].y += u.y * wm;
                acc[r].z += u.z * wm; acc[r].w += u.w * wm;
            }
        }
        #pragma unroll
        for (int r = 0; r < 8; ++r) {
            int ji0  = 4 * (t + 128 * r);
            int addr = (ji0 >> 8) * 260 + (ji0 & 255);
            *(float4*)(&V3L[addr]) = acc[r];
        }
    }

    // ---- V2 row for this thread's xx: v2r[v] = sum_k U2[(w,xx,v),k]*w2[e,k,c]
    float w2r[P2];
    #pragma unroll
    for (int k = 0; k < P2; ++k) w2r[k] = w2[(e * P2 + k) * C_ + c];
    float v2r[16];
    #pragma unroll
    for (int v = 0; v < 16; ++v) {
        const float* u2p = U2 + (size_t)(w * 256 + xx * 16 + v) * P2;
        float s = 0.f;
        #pragma unroll
        for (int k = 0; k < P2; ++k) s += u2p[k] * w2r[k];
        v2r[v] = s;
    }
    const float w1s = w1[e * C_ + c];
    __syncthreads();

    // ---- chunk loop: 32 batch rows per chunk, 4 per thread ----
    for (int base = 0; base < cnt; base += 32) {
        float xr[4][16];
        #pragma unroll
        for (int r = 0; r < 4; ++r) {
            int slot = base + bs * 4 + r;
            if (slot < cnt) {
                int b = list_g[e * B_ + slot];
                const float4* xp = (const float4*)(x + ((size_t)b * C_ + c) * ELL);
                #pragma unroll
                for (int i4 = 0; i4 < 4; ++i4) {
                    float4 v = xp[i4];
                    xr[r][4 * i4 + 0] = v.x; xr[r][4 * i4 + 1] = v.y;
                    xr[r][4 * i4 + 2] = v.z; xr[r][4 * i4 + 3] = v.w;
                }
            } else {
                #pragma unroll
                for (int i = 0; i < 16; ++i) xr[r][i] = 0.f;
            }
        }

        float t2[4];
        #pragma unroll
        for (int r = 0; r < 4; ++r) t2[r] = 0.f;
        const float* v3p = &V3L[xx * 260];

        #pragma unroll
        for (int v = 0; v < 16; ++v) {
            float s[4];
            #pragma unroll
            for (int r = 0; r < 4; ++r) s[r] = v2r[v];
            #pragma unroll
            for (int i4 = 0; i4 < 4; ++i4) {
                float4 u = *(const float4*)(v3p + v * 16 + 4 * i4);
                #pragma unroll
                for (int r = 0; r < 4; ++r) {
                    s[r] += u.x * xr[r][4 * i4 + 0];
                    s[r] += u.y * xr[r][4 * i4 + 1];
                    s[r] += u.z * xr[r][4 * i4 + 2];
                    s[r] += u.w * xr[r][4 * i4 + 3];
                }
            }
            #pragma unroll
            for (int r = 0; r < 4; ++r) t2[r] += s[r] * xr[r][v];
        }

        // exchange: T2L[slot_local][xx]
        #pragma unroll
        for (int r = 0; r < 4; ++r) T2L[(bs * 4 + r) * 17 + xx] = t2[r];
        __syncthreads();

        if (t < 32) {
            int slot = base + t;
            if (slot < cnt) {
                int b = list_g[e * B_ + slot];
                const float* xp = x + ((size_t)b * C_ + c) * ELL;
                float t1 = 0.f;
                #pragma unroll
                for (int x2 = 0; x2 < 16; ++x2) {
                    float c1 = T2L[t * 17 + x2] + U1[w * 16 + x2] * w1s;
                    t1 += c1 * xp[x2];
                }
                out[(size_t)b * (C_ * EQ) + c * EQ + w] = t1;
            }
        }
        __syncthreads();
    }
}

// ---------------------------------------------------------------------------
extern "C" void kernel_launch(void* const* d_in, const int* in_sizes, int n_in,
                              void* d_out, int out_size, void* d_ws, size_t ws_size,
                              hipStream_t stream) {
    const float* x    = (const float*)d_in[0];
    const float* y    = (const float*)d_in[1];
    const float* U3   = (const float*)d_in[2];
    const float* U2   = (const float*)d_in[3];
    const float* U1   = (const float*)d_in[4];
    const float* wmax = (const float*)d_in[5];
    const float* w2   = (const float*)d_in[6];
    const float* w1   = (const float*)d_in[7];
    float* out = (float*)d_out;
    char*  ws  = (char*)d_ws;

    int* cnt_g  = (int*)(ws + WS_CNT);
    int* list_g = (int*)(ws + WS_LIST);

    k_lists<<<1, B_, 0, stream>>>(y, cnt_g, list_g);

    if (ws_size >= WS_NEED_B) {
        float* v3g = (float*)(ws + WS_V3G);
        k_v3g<<<dim3(24, E_, 4), 256, 0, stream>>>(U3, wmax, v3g);
        k_main<<<dim3(C_, E_, EQ), 128, 0, stream>>>(x, v3g, U2, U1, wmax, w2, w1,
                                                     cnt_g, list_g, out, 1);
    } else {
        float* u3t = (float*)(ws + WS_U3T);
        k_transposeU3<<<1104, 256, 0, stream>>>(U3, u3t);
        k_main<<<dim3(C_, E_, EQ), 128, 0, stream>>>(x, u3t, U2, U1, wmax, w2, w1,
                                                     cnt_g, list_g, out, 0);
    }
}

// Round 4
// 164.666 us; speedup vs baseline: 1.5585x; 1.0096x over previous
//
#include <hip/hip_runtime.h>

// Problem constants
#define B_    1024
#define C_    128
#define ELL   16
#define EQ    3
#define E_    10
#define P3    23
#define P2    5
#define NJI   12288   // EQ*ELL*ELL*ELL

// ws layout (bytes)
#define WS_CNT   0
#define WS_LIST  64
#define WS_U3T   65536                         // mode-a: U3 transposed [k][ji], 1.13 MB
#define WS_V3G   (2u << 20)                    // mode-b: V3[e][c][ji], 62.9 MB
#define WS_NEED_B ((size_t)WS_V3G + (size_t)E_ * C_ * NJI * 4)

// ---------------------------------------------------------------------------
// K1: bucket batch indices by element (y is exact one-hot fp32), pad each
// bucket to a multiple of 32 by replicating the last real index so k_main
// needs no load guards.
__global__ __launch_bounds__(B_) void k_lists(const float* __restrict__ y,
                                              int* __restrict__ cnt_g,
                                              int* __restrict__ list_g) {
    __shared__ int lcnt[E_];
    const int t = threadIdx.x;
    if (t < E_) lcnt[t] = 0;
    __syncthreads();
    int e = 0;
    #pragma unroll
    for (int j = 1; j < E_; ++j)
        if (y[t * E_ + j] > 0.5f) e = j;
    int slot = atomicAdd(&lcnt[e], 1);
    list_g[e * B_ + slot] = t;
    __syncthreads();
    if (t < E_) {
        int c0 = lcnt[t];
        cnt_g[t] = c0;
        int last = (c0 > 0) ? list_g[t * B_ + c0 - 1] : 0;
        int cp = (c0 + 31) & ~31;
        for (int s2 = c0; s2 < cp; ++s2) list_g[t * B_ + s2] = last;
    }
}

// ---------------------------------------------------------------------------
// K2 (mode b): v3g[(e*C+c)*NJI + ji] = sum_k U3[ji*23+k] * wmax[(e*23+k)*128+c]
// grid (24 ji-tiles of 512, E, 4 c-quarters), 256 threads.
// Thread owns ji0 = jibase+2t (46 U3 floats in regs); c handled in groups of
// 4 so wmax comes from LDS as uniform-address ds_read_b128 (broadcast, free).
__global__ __launch_bounds__(256, 4) void k_v3g(const float* __restrict__ U3,
                                                const float* __restrict__ wmax,
                                                float* __restrict__ v3g) {
    __shared__ __align__(16) float wsm[P3 * 32];
    const int t  = threadIdx.x;
    const int jibase = blockIdx.x * 512;
    const int e  = blockIdx.y;
    const int cq = blockIdx.z;          // c-quarter

    for (int idx = t; idx < P3 * 32; idx += 256) {
        int k = idx >> 5, cc = idx & 31;
        wsm[idx] = wmax[(e * P3 + k) * C_ + cq * 32 + cc];
    }

    const int ji0 = jibase + 2 * t;
    float u46[46];
    const float* up = U3 + (size_t)ji0 * P3;
    #pragma unroll
    for (int q = 0; q < 46; ++q) u46[q] = up[q];
    __syncthreads();

    float* vbase = v3g + (size_t)(e * C_ + cq * 32) * NJI + ji0;
    #pragma unroll
    for (int g = 0; g < 8; ++g) {
        float a0[4], a1[4];
        #pragma unroll
        for (int q = 0; q < 4; ++q) { a0[q] = 0.f; a1[q] = 0.f; }
        #pragma unroll
        for (int k = 0; k < P3; ++k) {
            float4 wk = *(const float4*)&wsm[k * 32 + g * 4];
            a0[0] += u46[k] * wk.x; a1[0] += u46[23 + k] * wk.x;
            a0[1] += u46[k] * wk.y; a1[1] += u46[23 + k] * wk.y;
            a0[2] += u46[k] * wk.z; a1[2] += u46[23 + k] * wk.z;
            a0[3] += u46[k] * wk.w; a1[3] += u46[23 + k] * wk.w;
        }
        #pragma unroll
        for (int q = 0; q < 4; ++q) {
            float2 o; o.x = a0[q]; o.y = a1[q];
            *(float2*)(vbase + (size_t)(g * 4 + q) * NJI) = o;
        }
    }
}

// ---------------------------------------------------------------------------
// K2 (mode a): transpose U3 [ji][k] -> U3T [k][ji]   (282624 = 1104*256)
__global__ void k_transposeU3(const float* __restrict__ U3, float* __restrict__ U3T) {
    int o = blockIdx.x * 256 + threadIdx.x;
    if (o < NJI * P3) {
        int ji = o / P3, k = o - ji * P3;
        U3T[k * NJI + ji] = U3[o];
    }
}

// ---------------------------------------------------------------------------
// K3: main contraction. grid (C_*EQ, E_), 128 threads (2 waves).
// bx = c*3 + w so the 3 w-blocks of one (e,c) are adjacent (L2 locality on
// the v3g slice and the x rows). V3 slice in LDS with row stride 260
// (260%32==4 -> conflict-free b128). xx = t>>3, bs = t&7; 4 rows/thread.
// launch_bounds(128,2): allow up to 256 VGPR so xr[4][16] stays in arch
// VGPRs (with (128,4) the compiler pushed it to AGPRs -> v_accvgpr traffic).
__global__ __launch_bounds__(128, 2) void k_main(
    const float* __restrict__ x, const float* __restrict__ u3x,
    const float* __restrict__ U2, const float* __restrict__ U1,
    const float* __restrict__ wmax, const float* __restrict__ w2,
    const float* __restrict__ w1, const int* __restrict__ cnt_g,
    const int* __restrict__ list_g, float* __restrict__ out, int mode_b) {

    __shared__ __align__(16) float V3L[16 * 260];  // 16,640 B
    __shared__ float T2L[32 * 17];                 //  2,176 B
    __shared__ __align__(16) float XL[32 * 20];    //  2,560 B

    const int t  = threadIdx.x;
    const int bx = blockIdx.x;
    const int w  = bx % 3, c = bx / 3;
    const int e  = blockIdx.y;
    const int xx = t >> 3, bs = t & 7;
    const int cnt  = cnt_g[e];
    const int cntp = (cnt + 31) & ~31;

    // ---- fill V3L (rows = xx in [0,16), cols = v*16+i in [0,256)) ----
    if (mode_b) {
        const float4* src = (const float4*)(u3x + (size_t)(e * C_ + c) * NJI + w * 4096);
        #pragma unroll
        for (int r = 0; r < 8; ++r) {
            int f = t + 128 * r;                   // f4 index 0..1023
            float4 u = src[f];
            int ji0  = 4 * f;
            int addr = (ji0 >> 8) * 260 + (ji0 & 255);
            *(float4*)(&V3L[addr]) = u;
        }
    } else {
        float4 acc[8];
        #pragma unroll
        for (int r = 0; r < 8; ++r) acc[r] = make_float4(0.f, 0.f, 0.f, 0.f);
        for (int k = 0; k < P3; ++k) {
            float wm = wmax[(e * P3 + k) * C_ + c];
            const float4* u3t4 = (const float4*)(u3x + (size_t)k * NJI + w * 4096);
            #pragma unroll
            for (int r = 0; r < 8; ++r) {
                float4 u = u3t4[t + 128 * r];
                acc[r].x += u.x * wm; acc[r].y += u.y * wm;
                acc[r].z += u.z * wm; acc[r].w += u.w * wm;
            }
        }
        #pragma unroll
        for (int r = 0; r < 8; ++r) {
            int ji0  = 4 * (t + 128 * r);
            int addr = (ji0 >> 8) * 260 + (ji0 & 255);
            *(float4*)(&V3L[addr]) = acc[r];
        }
    }

    // ---- v2r[v] = sum_k U2[(w,xx,v),k]*w2[e,k,c]  (contiguous 80-float read)
    float w2r[P2];
    #pragma unroll
    for (int k = 0; k < P2; ++k) w2r[k] = w2[(e * P2 + k) * C_ + c];
    float u2r[80];
    {
        const float4* u2p4 = (const float4*)(U2 + (size_t)(w * 256 + xx * 16) * P2);
        #pragma unroll
        for (int q = 0; q < 20; ++q) ((float4*)u2r)[q] = u2p4[q];
    }
    float v2r[16];
    #pragma unroll
    for (int v = 0; v < 16; ++v) {
        float s = 0.f;
        #pragma unroll
        for (int k = 0; k < P2; ++k) s += u2r[v * P2 + k] * w2r[k];
        v2r[v] = s;
    }
    // ---- v1r[i] = U1[w*16+i] * w1[e,c]  (block-uniform, hoisted for tail)
    float v1r[16];
    {
        const float w1s = w1[e * C_ + c];
        const float4* u1p = (const float4*)(U1 + w * 16);
        #pragma unroll
        for (int q = 0; q < 4; ++q) {
            float4 u = u1p[q];
            v1r[4 * q + 0] = u.x * w1s; v1r[4 * q + 1] = u.y * w1s;
            v1r[4 * q + 2] = u.z * w1s; v1r[4 * q + 3] = u.w * w1s;
        }
    }
    __syncthreads();

    // ---- chunk loop: 32 batch rows per chunk, 4 per thread (lists padded) --
    for (int base = 0; base < cntp; base += 32) {
        int bidx[4];
        #pragma unroll
        for (int r = 0; r < 4; ++r) bidx[r] = list_g[e * B_ + base + bs * 4 + r];

        float xr[4][16];
        #pragma unroll
        for (int r = 0; r < 4; ++r) {
            const float4* xp = (const float4*)(x + ((size_t)bidx[r] * C_ + c) * ELL);
            #pragma unroll
            for (int i4 = 0; i4 < 4; ++i4) {
                float4 v = xp[i4];
                xr[r][4 * i4 + 0] = v.x; xr[r][4 * i4 + 1] = v.y;
                xr[r][4 * i4 + 2] = v.z; xr[r][4 * i4 + 3] = v.w;
            }
        }
        if (xx == 0) {   // stash x rows for the tail (8 lanes, rows bs*4+r)
            #pragma unroll
            for (int r = 0; r < 4; ++r)
                #pragma unroll
                for (int i4 = 0; i4 < 4; ++i4)
                    *(float4*)(&XL[(bs * 4 + r) * 20 + 4 * i4]) =
                        make_float4(xr[r][4 * i4 + 0], xr[r][4 * i4 + 1],
                                    xr[r][4 * i4 + 2], xr[r][4 * i4 + 3]);
        }

        float t2[4];
        #pragma unroll
        for (int r = 0; r < 4; ++r) t2[r] = 0.f;
        const float* v3p = &V3L[xx * 260];

        #pragma unroll
        for (int v = 0; v < 16; ++v) {
            float s[4];
            #pragma unroll
            for (int r = 0; r < 4; ++r) s[r] = v2r[v];
            #pragma unroll
            for (int i4 = 0; i4 < 4; ++i4) {
                float4 u = *(const float4*)(v3p + v * 16 + 4 * i4);
                #pragma unroll
                for (int r = 0; r < 4; ++r) {
                    s[r] += u.x * xr[r][4 * i4 + 0];
                    s[r] += u.y * xr[r][4 * i4 + 1];
                    s[r] += u.z * xr[r][4 * i4 + 2];
                    s[r] += u.w * xr[r][4 * i4 + 3];
                }
            }
            #pragma unroll
            for (int r = 0; r < 4; ++r) t2[r] += s[r] * xr[r][v];
        }

        #pragma unroll
        for (int r = 0; r < 4; ++r) T2L[(bs * 4 + r) * 17 + xx] = t2[r];
        __syncthreads();

        if (t < 32) {
            float t1 = 0.f;
            #pragma unroll
            for (int q = 0; q < 4; ++q) {
                float4 xv = *(const float4*)(&XL[t * 20 + 4 * q]);
                t1 += (T2L[t * 17 + 4 * q + 0] + v1r[4 * q + 0]) * xv.x;
                t1 += (T2L[t * 17 + 4 * q + 1] + v1r[4 * q + 1]) * xv.y;
                t1 += (T2L[t * 17 + 4 * q + 2] + v1r[4 * q + 2]) * xv.z;
                t1 += (T2L[t * 17 + 4 * q + 3] + v1r[4 * q + 3]) * xv.w;
            }
            int slot = base + t;
            if (slot < cnt)
                out[(size_t)list_g[e * B_ + slot] * (C_ * EQ) + c * EQ + w] = t1;
        }
        __syncthreads();
    }
}

// ---------------------------------------------------------------------------
extern "C" void kernel_launch(void* const* d_in, const int* in_sizes, int n_in,
                              void* d_out, int out_size, void* d_ws, size_t ws_size,
                              hipStream_t stream) {
    const float* x    = (const float*)d_in[0];
    const float* y    = (const float*)d_in[1];
    const float* U3   = (const float*)d_in[2];
    const float* U2   = (const float*)d_in[3];
    const float* U1   = (const float*)d_in[4];
    const float* wmax = (const float*)d_in[5];
    const float* w2   = (const float*)d_in[6];
    const float* w1   = (const float*)d_in[7];
    float* out = (float*)d_out;
    char*  ws  = (char*)d_ws;

    int* cnt_g  = (int*)(ws + WS_CNT);
    int* list_g = (int*)(ws + WS_LIST);

    k_lists<<<1, B_, 0, stream>>>(y, cnt_g, list_g);

    if (ws_size >= WS_NEED_B) {
        float* v3g = (float*)(ws + WS_V3G);
        k_v3g<<<dim3(24, E_, 4), 256, 0, stream>>>(U3, wmax, v3g);
        k_main<<<dim3(C_ * EQ, E_), 128, 0, stream>>>(x, v3g, U2, U1, wmax, w2, w1,
                                                      cnt_g, list_g, out, 1);
    } else {
        float* u3t = (float*)(ws + WS_U3T);
        k_transposeU3<<<1104, 256, 0, stream>>>(U3, u3t);
        k_main<<<dim3(C_ * EQ, E_), 128, 0, stream>>>(x, u3t, U2, U1, wmax, w2, w1,
                                                      cnt_g, list_g, out, 0);
    }
}